// Round 1
// baseline (2429.413 us; speedup 1.0000x reference)
//
#include <hip/hip_runtime.h>
#include <stdint.h>
#include <stddef.h>

#define B_ 64
#define L_ 200
#define F_ 512
#define H_ 512
#define A_ 512
#define E_ 512
#define V_ 50257
#define T_ 21
#define D_ 1024
#define NBLK_LOG 786   /* ceil(V/64) */
#define NPART 3144     /* NBLK_LOG*4 waves */

typedef __attribute__((ext_vector_type(8))) short short8;
typedef __attribute__((ext_vector_type(4))) float f32x4;

__device__ __forceinline__ unsigned short f2b(float f) {
  unsigned int u = __builtin_bit_cast(unsigned int, f);
  u += 0x7FFFu + ((u >> 16) & 1u);
  return (unsigned short)(u >> 16);
}
__device__ __forceinline__ float b2f(unsigned short s) {
  unsigned int u = ((unsigned int)s) << 16;
  return __builtin_bit_cast(float, u);
}
__device__ __forceinline__ f32x4 mfma16(short8 a, short8 b, f32x4 c) {
  return __builtin_amdgcn_mfma_f32_16x16x32_bf16(a, b, c, 0, 0, 0);
}

/* ---------------- setup kernels ---------------- */

// f32 -> bf16 elementwise (vectorized by 4)
__global__ void k_cvt(const float* __restrict__ src, unsigned short* __restrict__ dst, int n4) {
  int i = blockIdx.x * blockDim.x + threadIdx.x;
  int stride = gridDim.x * blockDim.x;
  const float4* s4 = (const float4*)src;
  ushort4* d4 = (ushort4*)dst;
  for (; i < n4; i += stride) {
    float4 v = s4[i];
    ushort4 o;
    o.x = f2b(v.x); o.y = f2b(v.y); o.z = f2b(v.z); o.w = f2b(v.w);
    d4[i] = o;
  }
}

// src f32 (R,C) -> dst bf16 (C,R); R,C multiples of 64; grid (C/64, R/64), 256 thr
__global__ void k_transcvt(const float* __restrict__ src, unsigned short* __restrict__ dst, int R, int C) {
  __shared__ float tile[64][65];
  int cb = blockIdx.x * 64, rb = blockIdx.y * 64;
  int tx = threadIdx.x & 63, ty = threadIdx.x >> 6;
#pragma unroll
  for (int i = 0; i < 16; ++i) {
    int r = ty * 16 + i;
    tile[r][tx] = src[(size_t)(rb + r) * C + cb + tx];
  }
  __syncthreads();
#pragma unroll
  for (int i = 0; i < 16; ++i) {
    int c = ty * 16 + i;
    dst[(size_t)(cb + c) * R + rb + tx] = f2b(tile[tx][c]);
  }
}

// src f32 (R,C) -> dst f32 (C,R); grid (C/64, R/64)
__global__ void k_trans32(const float* __restrict__ src, float* __restrict__ dst, int R, int C) {
  __shared__ float tile[64][65];
  int cb = blockIdx.x * 64, rb = blockIdx.y * 64;
  int tx = threadIdx.x & 63, ty = threadIdx.x >> 6;
#pragma unroll
  for (int i = 0; i < 16; ++i) {
    int r = ty * 16 + i;
    tile[r][tx] = src[(size_t)(rb + r) * C + cb + tx];
  }
  __syncthreads();
#pragma unroll
  for (int i = 0; i < 16; ++i) {
    int c = ty * 16 + i;
    dst[(size_t)(cb + c) * R + rb + tx] = tile[tx][c];
  }
}

// enc (B,L,F) f32 -> encT2 (L,B,F) bf16 ; grid (L, B), 256 thr
__global__ void k_encT2(const float* __restrict__ enc, unsigned short* __restrict__ dst) {
  int l = blockIdx.x, b = blockIdx.y;
  const float* s = enc + ((size_t)b * L_ + l) * F_;
  unsigned short* d = dst + ((size_t)l * B_ + b) * F_;
  for (int f = threadIdx.x; f < F_; f += 256) d[f] = f2b(s[f]);
}

// enc_projT[l][a][b] = sum_f WaT[a][f] * encT2[l][b][f] ; grid (32, 200), 256 thr
__global__ __launch_bounds__(256) void k_encproj(const unsigned short* __restrict__ WaT,
                                                 const unsigned short* __restrict__ eT,
                                                 unsigned short* __restrict__ ep) {
  int ab = blockIdx.x * 16, l = blockIdx.y;
  int w = threadIdx.x >> 6, lane = threadIdx.x & 63;
  int ln15 = lane & 15, g = lane >> 4;
  f32x4 acc = {0.f, 0.f, 0.f, 0.f};
  const unsigned short* arow = WaT + (size_t)(ab + ln15) * F_ + 8 * g;
  const unsigned short* brow = eT + ((size_t)l * B_ + w * 16 + ln15) * F_ + 8 * g;
#pragma unroll 4
  for (int kk = 0; kk < 16; ++kk) {
    short8 af = *(const short8*)(arow + kk * 32);
    short8 bf = *(const short8*)(brow + kk * 32);
    acc = mfma16(af, bf, acc);
  }
  unsigned short* dp = ep + ((size_t)l * A_ + ab + 4 * g) * B_ + w * 16 + ln15;
#pragma unroll
  for (int r = 0; r < 4; ++r) dp[(size_t)r * B_] = f2b(acc[r]);
}

// out[:,0,:] = 0 ; grid (50, 64), 256 thr
__global__ void k_zero0(float* __restrict__ out) {
  int b = blockIdx.y;
  float* o = out + (size_t)b * T_ * V_;
  int v0 = blockIdx.x * 1024 + threadIdx.x;
#pragma unroll
  for (int i = 0; i < 4; ++i) { int v = v0 + i * 256; if (v < V_) o[v] = 0.f; }
}

/* ---------------- per-step kernels ---------------- */

// x[b][0:512] = bf16(embed[word_b]) ; grid 64, 256 thr
__global__ void k_emb(const int* __restrict__ ref, const float* __restrict__ et,
                      unsigned short* __restrict__ xbf, int t) {
  int b = blockIdx.x;
  int word = ref[b * T_ + t];
  const float* s = et + (size_t)word * E_;
  unsigned short* d = xbf + (size_t)b * D_;
  for (int k = threadIdx.x; k < E_; k += 256) d[k] = f2b(s[k]);
}

// hWT[a][b] = sum_k WahT[a][k]*h[b][k] ; grid 32, 256 thr
__global__ __launch_bounds__(256) void k_hw(const unsigned short* __restrict__ WahT,
                                            const unsigned short* __restrict__ hb,
                                            float* __restrict__ hWT) {
  int ab = blockIdx.x * 16;
  int w = threadIdx.x >> 6, lane = threadIdx.x & 63;
  int ln15 = lane & 15, g = lane >> 4;
  f32x4 acc = {0.f, 0.f, 0.f, 0.f};
  const unsigned short* arow = WahT + (size_t)(ab + ln15) * H_ + 8 * g;
  const unsigned short* brow = hb + (size_t)(w * 16 + ln15) * H_ + 8 * g;
#pragma unroll 4
  for (int kk = 0; kk < 16; ++kk) {
    short8 af = *(const short8*)(arow + kk * 32);
    short8 bf = *(const short8*)(brow + kk * 32);
    acc = mfma16(af, bf, acc);
  }
  float* dp = hWT + (size_t)(ab + 4 * g) * B_ + w * 16 + ln15;
#pragma unroll
  for (int r = 0; r < 4; ++r) dp[(size_t)r * B_] = acc[r];
}

// scoreT[l][b] = sum_a tanh(ep[l][a][b] + hWT[a][b]) * v[a] (masked) ; grid 200, 256 thr
__global__ __launch_bounds__(256) void k_score(const unsigned short* __restrict__ ep,
                                               const float* __restrict__ hWT,
                                               const float* __restrict__ vatt,
                                               const float* __restrict__ mask,
                                               float* __restrict__ scoreT) {
  int l = blockIdx.x;
  int w = threadIdx.x >> 6, b = threadIdx.x & 63;
  const unsigned short* epb = ep + (size_t)l * A_ * B_ + b;
  const float* hwb = hWT + b;
  float p = 0.f;
  for (int a = w * 128; a < w * 128 + 128; ++a) {
    float x = b2f(epb[(size_t)a * B_]) + hwb[(size_t)a * B_];
    float e2 = __expf(x + x);
    float th = 1.f - 2.f / (e2 + 1.f);
    p += th * vatt[a];
  }
  __shared__ float part[4][64];
  part[w][b] = p;
  __syncthreads();
  if (threadIdx.x < 64) {
    float s = part[0][b] + part[1][b] + part[2][b] + part[3][b];
    float mk = mask[b * L_ + l];
    scoreT[l * B_ + b] = (mk > 0.f) ? s : -1e9f;
  }
}

// softmax over L + ctx[b][f] -> x[b][512+f] ; grid 64, 512 thr
__global__ __launch_bounds__(512) void k_ctx(const float* __restrict__ scoreT,
                                             const float* __restrict__ enc,
                                             unsigned short* __restrict__ xbf) {
  int b = blockIdx.x;
  int tid = threadIdx.x;
  __shared__ float sm[L_];
  __shared__ float red[2];
  if (tid < L_) sm[tid] = scoreT[tid * B_ + b];
  __syncthreads();
  if (tid < 64) {
    float m = -1e30f;
    for (int l = tid; l < L_; l += 64) m = fmaxf(m, sm[l]);
    for (int o = 1; o < 64; o <<= 1) m = fmaxf(m, __shfl_xor(m, o));
    if (tid == 0) red[0] = m;
  }
  __syncthreads();
  float m = red[0];
  if (tid < L_) sm[tid] = __expf(sm[tid] - m);
  __syncthreads();
  if (tid < 64) {
    float s = 0.f;
    for (int l = tid; l < L_; l += 64) s += sm[l];
    for (int o = 1; o < 64; o <<= 1) s += __shfl_xor(s, o);
    if (tid == 0) red[1] = s;
  }
  __syncthreads();
  float inv = 1.f / red[1];
  const float* eb = enc + (size_t)b * L_ * F_ + tid;
  float acc = 0.f;
#pragma unroll 4
  for (int l = 0; l < L_; ++l) acc += sm[l] * eb[(size_t)l * F_];
  xbf[(size_t)b * D_ + E_ + tid] = f2b(acc * inv);
}

// fused GRU cell ; grid 32 (j-chunks of 16), 256 thr (4 b-tiles)
__global__ __launch_bounds__(256) void k_gru(
    const unsigned short* __restrict__ Wihb, const unsigned short* __restrict__ Whhb,
    const unsigned short* __restrict__ xbf, const unsigned short* __restrict__ hbold,
    const float* __restrict__ hTold, const float* __restrict__ bih,
    const float* __restrict__ bhh, float* __restrict__ hTnew) {
  int jb = blockIdx.x * 16;
  int w = threadIdx.x >> 6, lane = threadIdx.x & 63;
  int ln15 = lane & 15, g = lane >> 4;
  f32x4 z4 = {0.f, 0.f, 0.f, 0.f};
  f32x4 aIr = z4, aIz = z4, aIn = z4, aHr = z4, aHz = z4, aHn = z4;
  {
    const unsigned short* xr = xbf + (size_t)(w * 16 + ln15) * D_ + 8 * g;
    const unsigned short* wir = Wihb + (size_t)(jb + ln15) * D_ + 8 * g;
    const unsigned short* wiz = Wihb + (size_t)(512 + jb + ln15) * D_ + 8 * g;
    const unsigned short* win = Wihb + (size_t)(1024 + jb + ln15) * D_ + 8 * g;
#pragma unroll 2
    for (int kk = 0; kk < 32; ++kk) {
      short8 xf = *(const short8*)(xr + kk * 32);
      aIr = mfma16(*(const short8*)(wir + kk * 32), xf, aIr);
      aIz = mfma16(*(const short8*)(wiz + kk * 32), xf, aIz);
      aIn = mfma16(*(const short8*)(win + kk * 32), xf, aIn);
    }
  }
  {
    const unsigned short* hr0 = hbold + (size_t)(w * 16 + ln15) * H_ + 8 * g;
    const unsigned short* whr = Whhb + (size_t)(jb + ln15) * H_ + 8 * g;
    const unsigned short* whz = Whhb + (size_t)(512 + jb + ln15) * H_ + 8 * g;
    const unsigned short* whn = Whhb + (size_t)(1024 + jb + ln15) * H_ + 8 * g;
#pragma unroll 2
    for (int kk = 0; kk < 16; ++kk) {
      short8 hf = *(const short8*)(hr0 + kk * 32);
      aHr = mfma16(*(const short8*)(whr + kk * 32), hf, aHr);
      aHz = mfma16(*(const short8*)(whz + kk * 32), hf, aHz);
      aHn = mfma16(*(const short8*)(whn + kk * 32), hf, aHn);
    }
  }
#pragma unroll
  for (int r = 0; r < 4; ++r) {
    int j = jb + 4 * g + r;
    int b = w * 16 + ln15;
    float ir = aIr[r] + bih[j];
    float iz = aIz[r] + bih[512 + j];
    float in_ = aIn[r] + bih[1024 + j];
    float hrv = aHr[r] + bhh[j];
    float hzv = aHz[r] + bhh[512 + j];
    float hnv = aHn[r] + bhh[1024 + j];
    float rg = 1.f / (1.f + __expf(-(ir + hrv)));
    float zg = 1.f / (1.f + __expf(-(iz + hzv)));
    float e2 = __expf(2.f * (in_ + rg * hnv));
    float ng = 1.f - 2.f / (e2 + 1.f);
    float ho = hTold[(size_t)j * B_ + b];
    hTnew[(size_t)j * B_ + b] = (1.f - zg) * ng + zg * ho;
  }
}

// hT f32 (H,B) -> hb bf16 (B,H) ; grid 8, 256 thr
__global__ void k_h2b(const float* __restrict__ hT, unsigned short* __restrict__ hb) {
  __shared__ float tile[64][65];
  int jc = blockIdx.x * 64;
  int tx = threadIdx.x & 63, ty = threadIdx.x >> 6;
#pragma unroll
  for (int i = 0; i < 16; ++i) {
    int jl = ty * 16 + i;
    tile[jl][tx] = hT[(size_t)(jc + jl) * B_ + tx];
  }
  __syncthreads();
#pragma unroll
  for (int i = 0; i < 16; ++i) {
    int bl = ty * 16 + i;
    hb[(size_t)bl * H_ + jc + tx] = f2b(tile[tx][bl]);
  }
}

// logits = h @ Wout^T + b, write to out plane, emit per-wave (max,sumexp) partials
// grid 786, 256 thr; 64 KB LDS for h (XOR-swizzled)
__global__ __launch_bounds__(256) void k_logits(const unsigned short* __restrict__ Wb,
                                                const unsigned short* __restrict__ hb,
                                                const float* __restrict__ bout,
                                                float* __restrict__ out,
                                                float* __restrict__ pm, float* __restrict__ ps,
                                                int tplane) {
  __shared__ unsigned short hl[32768];  // 64 rows x 1024B, swizzled
  int tid = threadIdx.x;
  for (int idx = tid; idx < 4096; idx += 256) {
    int row = idx >> 6, seg = idx & 63;
    unsigned char* dp = (unsigned char*)hl + row * 1024 + ((seg * 16) ^ ((row & 7) << 4));
    *(short8*)dp = *(const short8*)(hb + (size_t)row * H_ + seg * 8);
  }
  __syncthreads();
  int w = tid >> 6, lane = tid & 63;
  int ln15 = lane & 15, g = lane >> 4;
  int vcol = blockIdx.x * 64 + w * 16 + ln15;
  bool vok = vcol < V_;
  int vr = vok ? vcol : (V_ - 1);
  f32x4 z4 = {0.f, 0.f, 0.f, 0.f};
  f32x4 acc[4] = {z4, z4, z4, z4};
  const unsigned short* brow = Wb + (size_t)vr * H_ + 8 * g;
  int sw = (ln15 & 7) << 4;
  const unsigned char* hlb = (const unsigned char*)hl;
#pragma unroll 4
  for (int kk = 0; kk < 16; ++kk) {
    short8 bf = *(const short8*)(brow + kk * 32);
    int kb = kk * 64 + 16 * g;
#pragma unroll
    for (int mt = 0; mt < 4; ++mt) {
      short8 af = *(const short8*)(hlb + (mt * 16 + ln15) * 1024 + (kb ^ sw));
      acc[mt] = mfma16(af, bf, acc[mt]);
    }
  }
  float bo = bout[vr];
  int pbase = blockIdx.x * 4 + w;
#pragma unroll
  for (int mt = 0; mt < 4; ++mt) {
#pragma unroll
    for (int r = 0; r < 4; ++r) {
      float val = acc[mt][r] + bo;
      int bi = mt * 16 + 4 * g + r;
      if (vok) out[((size_t)bi * T_ + tplane) * V_ + vcol] = val;
      float pv = vok ? val : -1e30f;
      float mx = pv;
      for (int o = 1; o < 16; o <<= 1) mx = fmaxf(mx, __shfl_xor(mx, o));
      float e = __expf(pv - mx);
      for (int o = 1; o < 16; o <<= 1) e += __shfl_xor(e, o);
      if (ln15 == 0) {
        pm[bi * NPART + pbase] = mx;
        ps[bi * NPART + pbase] = e;
      }
    }
  }
}

// merge partials -> lse[b] ; grid 64, 256 thr
__global__ __launch_bounds__(256) void k_lse(const float* __restrict__ pm,
                                             const float* __restrict__ ps,
                                             float* __restrict__ lse) {
  int b = blockIdx.x;
  int tid = threadIdx.x;
  float m = -1e38f, s = 0.f;
  for (int p = tid; p < NPART; p += 256) {
    float pmv = pm[b * NPART + p], psv = ps[b * NPART + p];
    float nm = fmaxf(m, pmv);
    s = s * __expf(m - nm) + psv * __expf(pmv - nm);
    m = nm;
  }
  __shared__ float lm[256], ls2[256];
  lm[tid] = m; ls2[tid] = s;
  __syncthreads();
  for (int o = 128; o > 0; o >>= 1) {
    if (tid < o) {
      float m2 = lm[tid + o], s2 = ls2[tid + o];
      float nm = fmaxf(lm[tid], m2);
      ls2[tid] = ls2[tid] * __expf(lm[tid] - nm) + s2 * __expf(m2 - nm);
      lm[tid] = nm;
    }
    __syncthreads();
  }
  if (tid == 0) lse[b] = lm[0] + logf(ls2[0]);
}

// out[b][tplane][v] -= lse[b] ; grid (50, 64), 256 thr
__global__ void k_fin(float* __restrict__ out, const float* __restrict__ lse, int tplane) {
  int b = blockIdx.y;
  float Lv = lse[b];
  float* o = out + ((size_t)b * T_ + tplane) * V_;
  int v0 = blockIdx.x * 1024 + threadIdx.x;
#pragma unroll
  for (int i = 0; i < 4; ++i) { int v = v0 + i * 256; if (v < V_) o[v] -= Lv; }
}

/* ---------------- host ---------------- */

extern "C" void kernel_launch(void* const* d_in, const int* in_sizes, int n_in,
                              void* d_out, int out_size, void* d_ws, size_t ws_size,
                              hipStream_t stream) {
  const float* enc   = (const float*)d_in[0];
  const float* dih   = (const float*)d_in[1];
  const float* mask  = (const float*)d_in[2];
  const float* et    = (const float*)d_in[4];
  const float* Wih   = (const float*)d_in[5];
  const float* Whh   = (const float*)d_in[6];
  const float* bih   = (const float*)d_in[7];
  const float* bhh   = (const float*)d_in[8];
  const float* Waenc = (const float*)d_in[9];
  const float* Wah   = (const float*)d_in[10];
  const float* vatt  = (const float*)d_in[11];
  const float* Wout  = (const float*)d_in[12];
  const float* bout  = (const float*)d_in[13];
  const int*   ref   = (const int*)d_in[14];
  float* out = (float*)d_out;

  char* w = (char*)d_ws;
  size_t o = 0;
  unsigned short* Wb    = (unsigned short*)(w + o); o += (size_t)V_ * H_ * 2;
  unsigned short* Wihb  = (unsigned short*)(w + o); o += (size_t)1536 * 1024 * 2;
  unsigned short* Whhb  = (unsigned short*)(w + o); o += (size_t)1536 * 512 * 2;
  unsigned short* WaTb  = (unsigned short*)(w + o); o += (size_t)512 * 512 * 2;
  unsigned short* WahTb = (unsigned short*)(w + o); o += (size_t)512 * 512 * 2;
  unsigned short* encT2 = (unsigned short*)(w + o); o += (size_t)L_ * B_ * F_ * 2;
  unsigned short* epT   = (unsigned short*)(w + o); o += (size_t)L_ * A_ * B_ * 2;
  float* hT0 = (float*)(w + o); o += (size_t)H_ * B_ * 4;
  float* hT1 = (float*)(w + o); o += (size_t)H_ * B_ * 4;
  unsigned short* hb0 = (unsigned short*)(w + o); o += (size_t)B_ * H_ * 2;
  unsigned short* hb1 = (unsigned short*)(w + o); o += (size_t)B_ * H_ * 2;
  unsigned short* xbf = (unsigned short*)(w + o); o += (size_t)B_ * D_ * 2;
  float* hWT    = (float*)(w + o); o += (size_t)A_ * B_ * 4;
  float* scoreT = (float*)(w + o); o += (size_t)L_ * B_ * 4;
  float* pm     = (float*)(w + o); o += (size_t)B_ * NPART * 4;
  float* ps     = (float*)(w + o); o += (size_t)B_ * NPART * 4;
  float* lse    = (float*)(w + o); o += 256;

  float* hT[2] = {hT0, hT1};
  unsigned short* hb[2] = {hb0, hb1};

  // one-time setup (recomputed each call for determinism)
  k_cvt<<<4096, 256, 0, stream>>>(Wout, Wb, V_ * H_ / 4);
  k_cvt<<<1024, 256, 0, stream>>>(Wih, Wihb, 1536 * 1024 / 4);
  k_cvt<<<512, 256, 0, stream>>>(Whh, Whhb, 1536 * 512 / 4);
  k_cvt<<<64, 256, 0, stream>>>(dih, hb0, B_ * H_ / 4);
  k_transcvt<<<dim3(8, 8), 256, 0, stream>>>(Waenc, WaTb, 512, 512);
  k_transcvt<<<dim3(8, 8), 256, 0, stream>>>(Wah, WahTb, 512, 512);
  k_trans32<<<dim3(8, 1), 256, 0, stream>>>(dih, hT0, 64, 512);
  k_encT2<<<dim3(L_, B_), 256, 0, stream>>>(enc, encT2);
  k_encproj<<<dim3(32, L_), 256, 0, stream>>>(WaTb, encT2, epT);
  k_zero0<<<dim3(50, 64), 256, 0, stream>>>(out);

  for (int t = 0; t < T_ - 1; ++t) {
    int cur = t & 1, nxt = cur ^ 1;
    k_emb<<<64, 256, 0, stream>>>(ref, et, xbf, t);
    k_hw<<<32, 256, 0, stream>>>(WahTb, hb[cur], hWT);
    k_score<<<L_, 256, 0, stream>>>(epT, hWT, vatt, mask, scoreT);
    k_ctx<<<64, 512, 0, stream>>>(scoreT, enc, xbf);
    k_gru<<<32, 256, 0, stream>>>(Wihb, Whhb, xbf, hb[cur], hT[cur], bih, bhh, hT[nxt]);
    k_h2b<<<8, 256, 0, stream>>>(hT[nxt], hb[nxt]);
    k_logits<<<NBLK_LOG, 256, 0, stream>>>(Wb, hb[nxt], bout, out, pm, ps, t + 1);
    k_lse<<<64, 256, 0, stream>>>(pm, ps, lse);
    k_fin<<<dim3(50, 64), 256, 0, stream>>>(out, lse, t + 1);
  }
}